// Round 1
// baseline (97.368 us; speedup 1.0000x reference)
//
#include <hip/hip_runtime.h>
#include <math.h>

#define WIN 11
#define HALF 5
#define SZ 32
#define PST 33          /* padded LDS row stride */
#define BB 4
#define NG 16
#define NP 64
#define IH 640
#define IW 640
#define CPIX 1024       /* 32*32 per channel */
#define NPIX 3072       /* 3*32*32 per crop */
#define NCROP 320       /* 64 gt + 256 pred */
#define NPAIR 4096      /* 4*16*64 */
#define NSLOT 512       /* k_pair y-blocks per channel */
#define SSIM_C1 6.5025f
#define SSIM_C2 58.5225f

// exp(-(i-5)^2/4.5)/sum — 11-tap Gaussian, sigma=1.5, compile-time
#define GW_INIT {0.001028379f, 0.007598757f, 0.036000791f, 0.109360748f, \
                 0.213005174f, 0.266011868f, 0.213005174f, 0.109360748f, \
                 0.036000791f, 0.007598757f, 0.001028379f}

// Session lessons encoded:
//  - NO __threadfence (r5: device-scope fence flushes per-XCD L2; +100 µs over 1.5k blocks).
//  - NO contended fp atomicAdd accumulation (r2/r6 vs r3/r7: +16 µs); unique-cell
//    stores + reduce.
//  - NO memset dispatch: ballot compaction writes count/list with plain stores.
//  - r8: do NOT re-gather crops per pair (scattered gathers are the expensive op).
//  - r9: do NOT move per-crop stats (mu/sigma convs) into the per-pair kernel
//    (2.8x conv work + 30KB LDS = +6 µs). Compute each quantity at the loop
//    level where it naturally lives. r7 split is optimal so far.
//  - r10: bilinear gather via float2 (16->8 load instrs; clamp edges have
//    weight exactly 0 so result is bitwise identical).
//  - r11 (this round): fold k_final into k_pair via uncontended device-scope
//    ticket. Per-(slot,c) results published with AGENT-scope atomic stores
//    (bypass per-XCD L2 -> no fence needed); last participant (ACQ_REL
//    fetch_add on ticket) reduces and writes out. Removes one dispatch +
//    kernel-boundary flush. Ticket zeroed by the validity block of
//    k_crop_valid (strictly ordered before k_pair).

__device__ __forceinline__ bool pair_valid(const float* __restrict__ gt,
                                           const float* __restrict__ pr, int idx) {
    int b = idx >> 10;
    int r = idx & 1023;
    int gi = r >> 6, pi = r & 63;
    const float* g = gt + (b * NG + gi) * 4;
    const float* p = pr + (b * NP + pi) * 4;
    float gx = g[0], gy = g[1], gw = g[2], gh = g[3];
    float px = p[0], py = p[1], pw = p[2], ph = p[3];
    float tlx = fmaxf(gx - gw * 0.5f, px - pw * 0.5f);
    float tly = fmaxf(gy - gh * 0.5f, py - ph * 0.5f);
    float brx = fminf(gx + gw * 0.5f, px + pw * 0.5f);
    float bry = fminf(gy + gh * 0.5f, py + ph * 0.5f);
    float en = ((tlx < brx) && (tly < bry)) ? 1.f : 0.f;
    float ai = (brx - tlx) * (bry - tly) * en;
    float iou = ai / (gw * gh + pw * ph - ai + 1e-16f);
    return (iou > 0.3f && pw > 2.f && ph > 2.f);
}

// ---- fused: crop + mu/sigma (blocks 0..959) | validity compaction (block 960) ----
__global__ __launch_bounds__(256) void k_crop_valid(const float* __restrict__ imgs,
                                                    const float* __restrict__ gt,
                                                    const float* __restrict__ pr,
                                                    float* __restrict__ crops,
                                                    float* __restrict__ mus,
                                                    float* __restrict__ sigs,
                                                    int* __restrict__ list,
                                                    int* __restrict__ count,
                                                    int* __restrict__ ticket) {
    const int blk = blockIdx.x;
    const int t = threadIdx.x;
    const int wave = t >> 6, lane = t & 63;

    if (blk == 3 * NCROP) {
        // ---- validity -> compact list: 2-pass wave-local ballot, 1 barrier ----
        __shared__ int s_wcnt[4];
        int cnt = 0;
#pragma unroll 1
        for (int i = 0; i < 16; ++i) {
            unsigned long long m = __ballot(pair_valid(gt, pr, wave * 1024 + i * 64 + lane));
            cnt += __popcll(m);
        }
        if (lane == 0) s_wcnt[wave] = cnt;
        __syncthreads();
        int base = 0;
#pragma unroll
        for (int w = 0; w < 4; ++w)
            if (w < wave) base += s_wcnt[w];
#pragma unroll 1
        for (int i = 0; i < 16; ++i) {
            int idx = wave * 1024 + i * 64 + lane;
            bool v = pair_valid(gt, pr, idx);
            unsigned long long m = __ballot(v);
            if (v) list[base + __popcll(m & ((1ull << lane) - 1ull))] = idx;
            base += __popcll(m);
        }
        if (t == 0) {
            *count = s_wcnt[0] + s_wcnt[1] + s_wcnt[2] + s_wcnt[3];
            *ticket = 0;   // zero the k_pair completion ticket (poisoned ws)
        }
        return;
    }

    // ---- crop path: per-thread bilinear indices, float2 gathers ----
    const int crop = blk / 3;
    const int c = blk - crop * 3;
    int b;
    const float* box;
    if (crop < BB * NG) {
        b = crop >> 4;
        box = gt + crop * 4;
    } else {
        int id = crop - BB * NG;
        b = id >> 6;
        box = pr + id * 4;
    }

    __shared__ float cr[SZ][PST];
    __shared__ float t1[SZ][PST];
    __shared__ float t2[SZ][PST];

    // box is wave-uniform -> scalar loads
    float cx = box[0], cy = box[1], bw = box[2], bh = box[3];
    float x0 = fminf(fmaxf(floorf(cx - bw * 0.5f), 0.f), (float)(IW - 1));
    float x1 = fminf(fmaxf(floorf(cx + bw * 0.5f), 0.f), (float)IW);
    float y0 = fminf(fmaxf(floorf(cy - bh * 0.5f), 0.f), (float)(IH - 1));
    float y1 = fminf(fmaxf(floorf(cy + bh * 0.5f), 0.f), (float)IH);
    float wp = fmaxf(x1 - x0, 1.f);
    float hp = fmaxf(y1 - y0, 1.f);
    int xmax = (int)(x0 + wp - 1.f);
    int ymax = (int)(y0 + hp - 1.f);

    const int y = t >> 3;          // thread owns pixels (y, xb..xb+3)
    const int xb = (t & 7) * 4;

    float sy = y0 + fminf(fmaxf(((float)y + 0.5f) * hp * (1.f / 32.f) - 0.5f, 0.f), hp - 1.f);
    float fly = floorf(sy);
    int iy0 = (int)fly;
    float fy = sy - fly;
    int iy1 = min(iy0 + 1, ymax);

    const float* ic = imgs + ((size_t)b * 3 + c) * IH * IW;
    const float* r0 = ic + iy0 * IW;
    const float* r1 = ic + iy1 * IW;
    float vv[4];
#pragma unroll
    for (int j = 0; j < 4; ++j) {
        int x = xb + j;
        float sx = x0 + fminf(fmaxf(((float)x + 0.5f) * wp * (1.f / 32.f) - 0.5f, 0.f), wp - 1.f);
        float flx = floorf(sx);
        int ix0 = (int)flx;
        float fx = sx - flx;
        // float2 gather: ix1==ix0+1 except at the clamp edge; clamped/degenerate
        // lanes have fx==0 or select f.y, so result is bitwise identical to the
        // 4-scalar-load version (0-weight taps multiply a finite value).
        int ixb = max(min(ix0, xmax - 1), 0);
        bool cl = (ix0 > ixb);     // ix0 was at xmax: duplicate high element
        float2 q0 = *(const float2*)(r0 + ixb);
        float2 q1 = *(const float2*)(r1 + ixb);
        float v00 = cl ? q0.y : q0.x;
        float v01 = q0.y;
        float v10 = cl ? q1.y : q1.x;
        float v11 = q1.y;
        vv[j] = v00 * (1.f - fy) * (1.f - fx) + v01 * (1.f - fy) * fx +
                v10 * fy * (1.f - fx) + v11 * fy * fx;
        cr[y][x] = vv[j];
    }
    float* dst = crops + (size_t)crop * NPIX + c * CPIX + t * 4;
    *(float4*)dst = make_float4(vv[0], vv[1], vv[2], vv[3]);
    __syncthreads();

    constexpr float GW[WIN] = GW_INIT;
    // horizontal pass on x and x^2
#pragma unroll
    for (int j = 0; j < 4; ++j) {
        int x = xb + j;
        float a1 = 0.f, a2 = 0.f;
#pragma unroll
        for (int k = 0; k < WIN; ++k) {
            int xx = x + k - HALF;
            if (xx >= 0 && xx < SZ) {
                float v = cr[y][xx];
                a1 += GW[k] * v;
                a2 += GW[k] * v * v;
            }
        }
        t1[y][x] = a1;
        t2[y][x] = a2;
    }
    __syncthreads();
    // vertical pass
    float m[4], s[4];
#pragma unroll
    for (int j = 0; j < 4; ++j) {
        int x = xb + j;
        float a1 = 0.f, a2 = 0.f;
#pragma unroll
        for (int k = 0; k < WIN; ++k) {
            int yy = y + k - HALF;
            if (yy >= 0 && yy < SZ) {
                a1 += GW[k] * t1[yy][x];
                a2 += GW[k] * t2[yy][x];
            }
        }
        m[j] = a1;
        s[j] = a2 - a1 * a1;
    }
    float* mdst = mus + (size_t)crop * NPIX + c * CPIX + t * 4;
    float* sdst = sigs + (size_t)crop * NPIX + c * CPIX + t * 4;
    *(float4*)mdst = make_float4(m[0], m[1], m[2], m[3]);
    *(float4*)sdst = make_float4(s[0], s[1], s[2], s[3]);
}

// ---- per-(valid-pair, channel) SSIM + L1; unique-cell agent-scope stores,
//      last participant (ticket) performs the final reduction in-place ----
__global__ __launch_bounds__(256) void k_pair(const int* __restrict__ list,
                                              const int* __restrict__ count,
                                              int* __restrict__ ticket,
                                              const float* __restrict__ crops,
                                              const float* __restrict__ mus,
                                              const float* __restrict__ sigs,
                                              float* __restrict__ pairL1,
                                              float* __restrict__ pairSS,
                                              float* __restrict__ out) {
    const int c = blockIdx.x;      // 0..2
    const int n = *count;
    const int t = threadIdx.x;
    const int y = t >> 3;
    const int xb = (t & 7) * 4;
    const int wave = t >> 6, lane = t & 63;

    // participants: y-blocks that do work (or the n==0 finalizer blocks y==0)
    const int nwork = (n > 0) ? (n < NSLOT ? n : NSLOT) : 1;
    if ((int)blockIdx.y >= nwork) return;   // idle blocks: no ticket, no barrier

    __shared__ float gp[SZ][PST];
    __shared__ float tmp[SZ][PST];
    __shared__ float rl[4], rs[4];
    __shared__ int s_last;
    constexpr float GW[WIN] = GW_INIT;

    for (int slot = blockIdx.y; slot < n; slot += NSLOT) {
        const int pair = list[slot];
        const int b = pair >> 10;
        const int r = pair & 1023;
        const int gi = r >> 6, pi = r & 63;
        const size_t goff = (size_t)(b * NG + gi) * NPIX + c * CPIX;
        const size_t poff = (size_t)(BB * NG + b * NP + pi) * NPIX + c * CPIX;

        float4 gv = *(const float4*)(crops + goff + t * 4);
        float4 pv = *(const float4*)(crops + poff + t * 4);
        // hoist mu/sigma loads: in flight across both conv phases
        float4 mg = *(const float4*)(mus + goff + t * 4);
        float4 mp = *(const float4*)(mus + poff + t * 4);
        float4 sg = *(const float4*)(sigs + goff + t * 4);
        float4 sp = *(const float4*)(sigs + poff + t * 4);

        float l1 = fabsf(gv.x - pv.x) + fabsf(gv.y - pv.y) +
                   fabsf(gv.z - pv.z) + fabsf(gv.w - pv.w);
        gp[y][xb + 0] = gv.x * pv.x;
        gp[y][xb + 1] = gv.y * pv.y;
        gp[y][xb + 2] = gv.z * pv.z;
        gp[y][xb + 3] = gv.w * pv.w;
        __syncthreads();

#pragma unroll
        for (int j = 0; j < 4; ++j) {
            int x = xb + j;
            float a = 0.f;
#pragma unroll
            for (int k = 0; k < WIN; ++k) {
                int xx = x + k - HALF;
                if (xx >= 0 && xx < SZ) a += GW[k] * gp[y][xx];
            }
            tmp[y][x] = a;
        }
        __syncthreads();

        float mgv[4] = {mg.x, mg.y, mg.z, mg.w};
        float mpv[4] = {mp.x, mp.y, mp.z, mp.w};
        float sgv[4] = {sg.x, sg.y, sg.z, sg.w};
        float spv[4] = {sp.x, sp.y, sp.z, sp.w};
        float ss = 0.f;
#pragma unroll
        for (int j = 0; j < 4; ++j) {
            int x = xb + j;
            float a = 0.f;
#pragma unroll
            for (int k = 0; k < WIN; ++k) {
                int yy = y + k - HALF;
                if (yy >= 0 && yy < SZ) a += GW[k] * tmp[yy][x];
            }
            float m1 = mgv[j], m2 = mpv[j];
            float sgp = a - m1 * m2;
            float num = (2.f * m1 * m2 + SSIM_C1) * (2.f * sgp + SSIM_C2);
            float den = (m1 * m1 + m2 * m2 + SSIM_C1) * (sgv[j] + spv[j] + SSIM_C2);
            ss += num / den;
        }

        // block reduction: 64-lane shuffle, then LDS across 4 waves
#pragma unroll
        for (int off = 32; off > 0; off >>= 1) {
            l1 += __shfl_down(l1, off);
            ss += __shfl_down(ss, off);
        }
        if (lane == 0) { rl[wave] = l1; rs[wave] = ss; }
        __syncthreads();
        if (t == 0) {
            // AGENT-scope stores: land at the coherent point (no per-XCD L2
            // residency) so the finalizer block reads them without fences.
            __hip_atomic_store(&pairL1[slot * 3 + c], rl[0] + rl[1] + rl[2] + rl[3],
                               __ATOMIC_RELAXED, __HIP_MEMORY_SCOPE_AGENT);
            __hip_atomic_store(&pairSS[slot * 3 + c], rs[0] + rs[1] + rs[2] + rs[3],
                               __ATOMIC_RELAXED, __HIP_MEMORY_SCOPE_AGENT);
        }
    }

    // ---- completion ticket: last participant does the final reduction ----
    if (t == 0) {
        int old = __hip_atomic_fetch_add(ticket, 1, __ATOMIC_ACQ_REL,
                                         __HIP_MEMORY_SCOPE_AGENT);
        s_last = (old == 3 * nwork - 1) ? 1 : 0;
    }
    __syncthreads();
    if (!s_last) return;

    const int n3 = n * 3;
    float L = 0.f, S = 0.f;
    for (int i = t; i < n3; i += 256) {
        L += __hip_atomic_load(&pairL1[i], __ATOMIC_RELAXED, __HIP_MEMORY_SCOPE_AGENT);
        S += __hip_atomic_load(&pairSS[i], __ATOMIC_RELAXED, __HIP_MEMORY_SCOPE_AGENT);
    }
#pragma unroll
    for (int off = 32; off > 0; off >>= 1) {
        L += __shfl_down(L, off);
        S += __shfl_down(S, off);
    }
    if (lane == 0) { rl[wave] = L; rs[wave] = S; }
    __syncthreads();
    if (t == 0) {
        float cnt = (float)n;
        float Lt = (rl[0] + rl[1] + rl[2] + rl[3]) * (1.0f / (255.0f * (float)NPIX));
        float St = (rs[0] + rs[1] + rs[2] + rs[3]) * (1.0f / (float)NPIX);
        float m = fmaxf(cnt, 1.f);
        float loss = Lt / m + 1.f - St / m;
        out[0] = (cnt > 0.f) ? loss : 0.f;
    }
}

extern "C" void kernel_launch(void* const* d_in, const int* in_sizes, int n_in,
                              void* d_out, int out_size, void* d_ws, size_t ws_size,
                              hipStream_t stream) {
    const float* imgs = (const float*)d_in[0];  // (4,3,640,640)
    const float* gt = (const float*)d_in[1];    // (4,16,4)
    const float* pr = (const float*)d_in[2];    // (4,64,4)

    float* ws = (float*)d_ws;
    float* crops = ws;                                   // 320*3072
    float* mus = crops + (size_t)NCROP * NPIX;
    float* sigs = mus + (size_t)NCROP * NPIX;
    float* pairL1 = sigs + (size_t)NCROP * NPIX;         // 4096*3
    float* pairSS = pairL1 + (size_t)NPAIR * 3;          // 4096*3
    int* list = (int*)(pairSS + (size_t)NPAIR * 3);      // 4096
    int* count = list + NPAIR;                           // 1
    int* ticket = count + 1;                             // 1

    k_crop_valid<<<3 * NCROP + 1, 256, 0, stream>>>(imgs, gt, pr, crops, mus, sigs,
                                                    list, count, ticket);
    k_pair<<<dim3(3, NSLOT), 256, 0, stream>>>(list, count, ticket, crops, mus, sigs,
                                               pairL1, pairSS, (float*)d_out);
}

// Round 3
// 85.623 us; speedup vs baseline: 1.1372x; 1.1372x over previous
//
#include <hip/hip_runtime.h>
#include <math.h>

#define WIN 11
#define HALF 5
#define SZ 32
#define PST 33          /* padded LDS row stride (row-apron arrays) */
#define PSTA 45         /* stride for column-apron arrays: 42 cols used, odd stride -> <=2-way bank alias (free, m136) */
#define APR 42          /* 32 + 2*5 apron */
#define BB 4
#define NG 16
#define NP 64
#define IH 640
#define IW 640
#define CPIX 1024       /* 32*32 per channel */
#define NPIX 3072       /* 3*32*32 per crop */
#define NCROP 320       /* 64 gt + 256 pred */
#define NPAIR 4096      /* 4*16*64 */
#define NSLOT 512       /* k_pair y-blocks per channel */
#define SSIM_C1 6.5025f
#define SSIM_C2 58.5225f

// exp(-(i-5)^2/4.5)/sum — 11-tap Gaussian, sigma=1.5, compile-time
#define GW_INIT {0.001028379f, 0.007598757f, 0.036000791f, 0.109360748f, \
                 0.213005174f, 0.266011868f, 0.213005174f, 0.109360748f, \
                 0.036000791f, 0.007598757f, 0.001028379f}

// Session lessons encoded:
//  - NO __threadfence (r5: device-scope fence flushes per-XCD L2; +100 µs over 1.5k blocks).
//  - NO contended fp atomicAdd accumulation (r2/r6 vs r3/r7: +16 µs); unique-cell
//    stores + tiny reduce kernel.
//  - NO memset dispatch: ballot compaction writes count/list with plain stores.
//  - r8: do NOT re-gather crops per pair (scattered gathers are the expensive op).
//  - r9: do NOT move per-crop stats (mu/sigma convs) into the per-pair kernel
//    (2.8x conv work + 30KB LDS = +6 µs). Compute each quantity at the loop
//    level where it naturally lives. r7 split is optimal so far.
//  - r10: bilinear gather via float2 (16->8 load instrs; clamp edges have
//    weight exactly 0 so result is bitwise identical).
//  - r11 FAILED (+8.6 µs): folding k_final into k_pair via a per-block
//    AGENT-scope ACQ_REL ticket. Device-scope ordered atomics writeback/
//    invalidate the issuing XCD's L2 (coherence point is L3) -> ~900 flushes.
//    Same family as r5. A 1-block k_final dispatch is CHEAPER than any
//    cross-block completion protocol. Keep 3 kernels.
//  - r12: zero-padded LDS aprons make all 11-tap conv taps unconditional
//    (out-of-range taps multiply exact 0.0f -> bitwise identical). Removes
//    ~88 v_cmp+v_cndmask per thread in each hot kernel.
//  - r13 (this round): r12 resubmitted verbatim — r12's bench was an infra
//    failure (container acquire), not a kernel verdict.

__device__ __forceinline__ bool pair_valid(const float* __restrict__ gt,
                                           const float* __restrict__ pr, int idx) {
    int b = idx >> 10;
    int r = idx & 1023;
    int gi = r >> 6, pi = r & 63;
    const float* g = gt + (b * NG + gi) * 4;
    const float* p = pr + (b * NP + pi) * 4;
    float gx = g[0], gy = g[1], gw = g[2], gh = g[3];
    float px = p[0], py = p[1], pw = p[2], ph = p[3];
    float tlx = fmaxf(gx - gw * 0.5f, px - pw * 0.5f);
    float tly = fmaxf(gy - gh * 0.5f, py - ph * 0.5f);
    float brx = fminf(gx + gw * 0.5f, px + pw * 0.5f);
    float bry = fminf(gy + gh * 0.5f, py + ph * 0.5f);
    float en = ((tlx < brx) && (tly < bry)) ? 1.f : 0.f;
    float ai = (brx - tlx) * (bry - tly) * en;
    float iou = ai / (gw * gh + pw * ph - ai + 1e-16f);
    return (iou > 0.3f && pw > 2.f && ph > 2.f);
}

// ---- fused: crop + mu/sigma (blocks 0..959) | validity compaction (block 960) ----
__global__ __launch_bounds__(256) void k_crop_valid(const float* __restrict__ imgs,
                                                    const float* __restrict__ gt,
                                                    const float* __restrict__ pr,
                                                    float* __restrict__ crops,
                                                    float* __restrict__ mus,
                                                    float* __restrict__ sigs,
                                                    int* __restrict__ list,
                                                    int* __restrict__ count) {
    const int blk = blockIdx.x;
    const int t = threadIdx.x;
    const int wave = t >> 6, lane = t & 63;

    if (blk == 3 * NCROP) {
        // ---- validity -> compact list: 2-pass wave-local ballot, 1 barrier ----
        __shared__ int s_wcnt[4];
        int cnt = 0;
#pragma unroll 1
        for (int i = 0; i < 16; ++i) {
            unsigned long long m = __ballot(pair_valid(gt, pr, wave * 1024 + i * 64 + lane));
            cnt += __popcll(m);
        }
        if (lane == 0) s_wcnt[wave] = cnt;
        __syncthreads();
        int base = 0;
#pragma unroll
        for (int w = 0; w < 4; ++w)
            if (w < wave) base += s_wcnt[w];
#pragma unroll 1
        for (int i = 0; i < 16; ++i) {
            int idx = wave * 1024 + i * 64 + lane;
            bool v = pair_valid(gt, pr, idx);
            unsigned long long m = __ballot(v);
            if (v) list[base + __popcll(m & ((1ull << lane) - 1ull))] = idx;
            base += __popcll(m);
        }
        if (t == 0) *count = s_wcnt[0] + s_wcnt[1] + s_wcnt[2] + s_wcnt[3];
        return;
    }

    // ---- crop path: per-thread bilinear indices, float2 gathers ----
    const int crop = blk / 3;
    const int c = blk - crop * 3;
    int b;
    const float* box;
    if (crop < BB * NG) {
        b = crop >> 4;
        box = gt + crop * 4;
    } else {
        int id = crop - BB * NG;
        b = id >> 6;
        box = pr + id * 4;
    }

    // cr: column apron (x index shifted +5, cols 0..41 valid, 0..4 & 37..41 zero)
    // t1/t2: row apron (y index shifted +5, rows 0..41, 0..4 & 37..41 zero)
    __shared__ float cr[SZ][PSTA];
    __shared__ float t1[APR][PST];
    __shared__ float t2[APR][PST];

    // zero conv aprons once (taps into apron multiply exact 0.0f)
    for (int i = t; i < SZ * 10; i += 256) {
        int r = i / 10, cc = i % 10;
        cr[r][cc < 5 ? cc : cc + 32] = 0.f;
    }
    for (int i = t; i < 10 * PST; i += 256) {
        int r = i / PST, cc = i % PST;
        int rr = (r < 5) ? r : r + 32;
        t1[rr][cc] = 0.f;
        t2[rr][cc] = 0.f;
    }

    // box is wave-uniform -> scalar loads
    float cx = box[0], cy = box[1], bw = box[2], bh = box[3];
    float x0 = fminf(fmaxf(floorf(cx - bw * 0.5f), 0.f), (float)(IW - 1));
    float x1 = fminf(fmaxf(floorf(cx + bw * 0.5f), 0.f), (float)IW);
    float y0 = fminf(fmaxf(floorf(cy - bh * 0.5f), 0.f), (float)(IH - 1));
    float y1 = fminf(fmaxf(floorf(cy + bh * 0.5f), 0.f), (float)IH);
    float wp = fmaxf(x1 - x0, 1.f);
    float hp = fmaxf(y1 - y0, 1.f);
    int xmax = (int)(x0 + wp - 1.f);
    int ymax = (int)(y0 + hp - 1.f);

    const int y = t >> 3;          // thread owns pixels (y, xb..xb+3)
    const int xb = (t & 7) * 4;

    float sy = y0 + fminf(fmaxf(((float)y + 0.5f) * hp * (1.f / 32.f) - 0.5f, 0.f), hp - 1.f);
    float fly = floorf(sy);
    int iy0 = (int)fly;
    float fy = sy - fly;
    int iy1 = min(iy0 + 1, ymax);

    const float* ic = imgs + ((size_t)b * 3 + c) * IH * IW;
    const float* r0 = ic + iy0 * IW;
    const float* r1 = ic + iy1 * IW;
    float vv[4];
#pragma unroll
    for (int j = 0; j < 4; ++j) {
        int x = xb + j;
        float sx = x0 + fminf(fmaxf(((float)x + 0.5f) * wp * (1.f / 32.f) - 0.5f, 0.f), wp - 1.f);
        float flx = floorf(sx);
        int ix0 = (int)flx;
        float fx = sx - flx;
        // float2 gather: ix1==ix0+1 except at the clamp edge; clamped/degenerate
        // lanes have fx==0 or select f.y, so result is bitwise identical to the
        // 4-scalar-load version (0-weight taps multiply a finite value).
        int ixb = max(min(ix0, xmax - 1), 0);
        bool cl = (ix0 > ixb);     // ix0 was at xmax: duplicate high element
        float2 q0 = *(const float2*)(r0 + ixb);
        float2 q1 = *(const float2*)(r1 + ixb);
        float v00 = cl ? q0.y : q0.x;
        float v01 = q0.y;
        float v10 = cl ? q1.y : q1.x;
        float v11 = q1.y;
        vv[j] = v00 * (1.f - fy) * (1.f - fx) + v01 * (1.f - fy) * fx +
                v10 * fy * (1.f - fx) + v11 * fy * fx;
        cr[y][x + 5] = vv[j];
    }
    float* dst = crops + (size_t)crop * NPIX + c * CPIX + t * 4;
    *(float4*)dst = make_float4(vv[0], vv[1], vv[2], vv[3]);
    __syncthreads();

    constexpr float GW[WIN] = GW_INIT;
    // horizontal pass on x and x^2 — unconditional taps (apron = 0)
#pragma unroll
    for (int j = 0; j < 4; ++j) {
        int x = xb + j;
        float a1 = 0.f, a2 = 0.f;
#pragma unroll
        for (int k = 0; k < WIN; ++k) {
            float v = cr[y][x + k];        // conceptual col x+k-5, stored +5
            a1 += GW[k] * v;
            a2 += GW[k] * v * v;
        }
        t1[y + 5][x] = a1;
        t2[y + 5][x] = a2;
    }
    __syncthreads();
    // vertical pass — unconditional taps (apron = 0)
    float m[4], s[4];
#pragma unroll
    for (int j = 0; j < 4; ++j) {
        int x = xb + j;
        float a1 = 0.f, a2 = 0.f;
#pragma unroll
        for (int k = 0; k < WIN; ++k) {
            a1 += GW[k] * t1[y + k][x];    // conceptual row y+k-5, stored +5
            a2 += GW[k] * t2[y + k][x];
        }
        m[j] = a1;
        s[j] = a2 - a1 * a1;
    }
    float* mdst = mus + (size_t)crop * NPIX + c * CPIX + t * 4;
    float* sdst = sigs + (size_t)crop * NPIX + c * CPIX + t * 4;
    *(float4*)mdst = make_float4(m[0], m[1], m[2], m[3]);
    *(float4*)sdst = make_float4(s[0], s[1], s[2], s[3]);
}

// ---- per-(valid-pair, channel) SSIM + L1; unique-cell stores (r3/r7-measured-fast) ----
__global__ __launch_bounds__(256) void k_pair(const int* __restrict__ list,
                                              const int* __restrict__ count,
                                              const float* __restrict__ crops,
                                              const float* __restrict__ mus,
                                              const float* __restrict__ sigs,
                                              float* __restrict__ pairL1,
                                              float* __restrict__ pairSS) {
    const int c = blockIdx.x;      // 0..2
    const int n = *count;
    const int t = threadIdx.x;
    const int y = t >> 3;
    const int xb = (t & 7) * 4;
    const int wave = t >> 6, lane = t & 63;

    __shared__ float gp[SZ][PSTA];
    __shared__ float tmp[APR][PST];
    __shared__ float rl[4], rs[4];
    constexpr float GW[WIN] = GW_INIT;

    // zero conv aprons once; interior is rewritten each slot iteration
    for (int i = t; i < SZ * 10; i += 256) {
        int r = i / 10, cc = i % 10;
        gp[r][cc < 5 ? cc : cc + 32] = 0.f;
    }
    for (int i = t; i < 10 * PST; i += 256) {
        int r = i / PST, cc = i % PST;
        int rr = (r < 5) ? r : r + 32;
        tmp[rr][cc] = 0.f;
    }

    for (int slot = blockIdx.y; slot < n; slot += NSLOT) {
        const int pair = list[slot];
        const int b = pair >> 10;
        const int r = pair & 1023;
        const int gi = r >> 6, pi = r & 63;
        const size_t goff = (size_t)(b * NG + gi) * NPIX + c * CPIX;
        const size_t poff = (size_t)(BB * NG + b * NP + pi) * NPIX + c * CPIX;

        float4 gv = *(const float4*)(crops + goff + t * 4);
        float4 pv = *(const float4*)(crops + poff + t * 4);
        // hoist mu/sigma loads: in flight across both conv phases
        float4 mg = *(const float4*)(mus + goff + t * 4);
        float4 mp = *(const float4*)(mus + poff + t * 4);
        float4 sg = *(const float4*)(sigs + goff + t * 4);
        float4 sp = *(const float4*)(sigs + poff + t * 4);

        float l1 = fabsf(gv.x - pv.x) + fabsf(gv.y - pv.y) +
                   fabsf(gv.z - pv.z) + fabsf(gv.w - pv.w);
        gp[y][xb + 5] = gv.x * pv.x;
        gp[y][xb + 6] = gv.y * pv.y;
        gp[y][xb + 7] = gv.z * pv.z;
        gp[y][xb + 8] = gv.w * pv.w;
        __syncthreads();

#pragma unroll
        for (int j = 0; j < 4; ++j) {
            int x = xb + j;
            float a = 0.f;
#pragma unroll
            for (int k = 0; k < WIN; ++k) a += GW[k] * gp[y][x + k];
            tmp[y + 5][x] = a;
        }
        __syncthreads();

        float mgv[4] = {mg.x, mg.y, mg.z, mg.w};
        float mpv[4] = {mp.x, mp.y, mp.z, mp.w};
        float sgv[4] = {sg.x, sg.y, sg.z, sg.w};
        float spv[4] = {sp.x, sp.y, sp.z, sp.w};
        float ss = 0.f;
#pragma unroll
        for (int j = 0; j < 4; ++j) {
            int x = xb + j;
            float a = 0.f;
#pragma unroll
            for (int k = 0; k < WIN; ++k) a += GW[k] * tmp[y + k][x];
            float m1 = mgv[j], m2 = mpv[j];
            float sgp = a - m1 * m2;
            float num = (2.f * m1 * m2 + SSIM_C1) * (2.f * sgp + SSIM_C2);
            float den = (m1 * m1 + m2 * m2 + SSIM_C1) * (sgv[j] + spv[j] + SSIM_C2);
            ss += num / den;
        }

        // block reduction: 64-lane shuffle, then LDS across 4 waves
#pragma unroll
        for (int off = 32; off > 0; off >>= 1) {
            l1 += __shfl_down(l1, off);
            ss += __shfl_down(ss, off);
        }
        if (lane == 0) { rl[wave] = l1; rs[wave] = ss; }
        __syncthreads();
        if (t == 0) {
            pairL1[slot * 3 + c] = rl[0] + rl[1] + rl[2] + rl[3];
            pairSS[slot * 3 + c] = rs[0] + rs[1] + rs[2] + rs[3];
        }
    }
}

// ---- finalize: deterministic reduction over compact results ----
__global__ __launch_bounds__(256) void k_final(const int* __restrict__ count,
                                               const float* __restrict__ pairL1,
                                               const float* __restrict__ pairSS,
                                               float* __restrict__ out) {
    const int n3 = (*count) * 3;
    const int t = threadIdx.x;
    float L = 0.f, S = 0.f;
    for (int i = t; i < n3; i += 256) {
        L += pairL1[i];
        S += pairSS[i];
    }
    __shared__ float rl[4], rs[4];
#pragma unroll
    for (int off = 32; off > 0; off >>= 1) {
        L += __shfl_down(L, off);
        S += __shfl_down(S, off);
    }
    const int wave = t >> 6, lane = t & 63;
    if (lane == 0) { rl[wave] = L; rs[wave] = S; }
    __syncthreads();
    if (t == 0) {
        float cnt = (float)(*count);
        float Lt = (rl[0] + rl[1] + rl[2] + rl[3]) * (1.0f / (255.0f * (float)NPIX));
        float St = (rs[0] + rs[1] + rs[2] + rs[3]) * (1.0f / (float)NPIX);
        float m = fmaxf(cnt, 1.f);
        float loss = Lt / m + 1.f - St / m;
        out[0] = (cnt > 0.f) ? loss : 0.f;
    }
}

extern "C" void kernel_launch(void* const* d_in, const int* in_sizes, int n_in,
                              void* d_out, int out_size, void* d_ws, size_t ws_size,
                              hipStream_t stream) {
    const float* imgs = (const float*)d_in[0];  // (4,3,640,640)
    const float* gt = (const float*)d_in[1];    // (4,16,4)
    const float* pr = (const float*)d_in[2];    // (4,64,4)

    float* ws = (float*)d_ws;
    float* crops = ws;                                   // 320*3072
    float* mus = crops + (size_t)NCROP * NPIX;
    float* sigs = mus + (size_t)NCROP * NPIX;
    float* pairL1 = sigs + (size_t)NCROP * NPIX;         // 4096*3
    float* pairSS = pairL1 + (size_t)NPAIR * 3;          // 4096*3
    int* list = (int*)(pairSS + (size_t)NPAIR * 3);      // 4096
    int* count = list + NPAIR;                           // 1

    k_crop_valid<<<3 * NCROP + 1, 256, 0, stream>>>(imgs, gt, pr, crops, mus, sigs,
                                                    list, count);
    k_pair<<<dim3(3, NSLOT), 256, 0, stream>>>(list, count, crops, mus, sigs,
                                               pairL1, pairSS);
    k_final<<<1, 256, 0, stream>>>(count, pairL1, pairSS, (float*)d_out);
}

// Round 4
// 81.735 us; speedup vs baseline: 1.1913x; 1.0476x over previous
//
#include <hip/hip_runtime.h>
#include <math.h>

#define WIN 11
#define HALF 5
#define SZ 32
#define PST 33          /* padded LDS row stride (row-apron arrays) */
#define PSTA 45         /* stride for column-apron arrays: 42 cols used, odd stride -> <=2-way bank alias (free, m136) */
#define APR 42          /* 32 + 2*5 apron */
#define BB 4
#define NG 16
#define NP 64
#define IH 640
#define IW 640
#define CPIX 1024       /* 32*32 per channel */
#define NPIX 3072       /* 3*32*32 per crop */
#define NCROP 320       /* 64 gt + 256 pred */
#define NPAIR 4096      /* 4*16*64 */
#define NSLOT 512       /* k_pair y-blocks per channel */
#define SSIM_C1 6.5025f
#define SSIM_C2 58.5225f

// exp(-(i-5)^2/4.5)/sum — 11-tap Gaussian, sigma=1.5, compile-time
#define GW_INIT {0.001028379f, 0.007598757f, 0.036000791f, 0.109360748f, \
                 0.213005174f, 0.266011868f, 0.213005174f, 0.109360748f, \
                 0.036000791f, 0.007598757f, 0.001028379f}

// Session lessons encoded:
//  - NO __threadfence (r5: device-scope fence flushes per-XCD L2; +100 µs over 1.5k blocks).
//  - NO contended fp atomicAdd accumulation (r2/r6 vs r3/r7: +16 µs); unique-cell
//    stores + tiny reduce kernel.
//  - NO memset dispatch: ballot compaction writes count/list with plain stores.
//  - r8: do NOT re-gather crops per pair (scattered gathers are the expensive op).
//  - r9: do NOT move per-crop stats (mu/sigma convs) into the per-pair kernel
//    (2.8x conv work + 30KB LDS = +6 µs). Compute each quantity at the loop
//    level where it naturally lives. r7 split is optimal so far.
//  - r10: bilinear gather via float2 (16->8 load instrs; clamp edges have
//    weight exactly 0 so result is bitwise identical).
//  - r11 FAILED (+8.6 µs): folding k_final into k_pair via a per-block
//    AGENT-scope ACQ_REL ticket. Device-scope ordered atomics writeback/
//    invalidate the issuing XCD's L2 (coherence point is L3) -> ~900 flushes.
//    Same family as r5. A 1-block k_final dispatch is CHEAPER than any
//    cross-block completion protocol. Keep 3 kernels.
//  - r12/r13 WIN (-3.2 µs): zero-padded LDS aprons -> unconditional conv taps
//    (apron taps multiply exact 0.0f, bitwise identical). 85.6 µs.
//  - r14 (this round): k_crop_valid at 512 threads (2 px/thread). Gathers hit
//    cold HBM (~900 cy) after the poison fill; at 256 thr/block the machine
//    held only ~15 waves/CU. Doubling resident waves doubles latency hiding.

__device__ __forceinline__ bool pair_valid(const float* __restrict__ gt,
                                           const float* __restrict__ pr, int idx) {
    int b = idx >> 10;
    int r = idx & 1023;
    int gi = r >> 6, pi = r & 63;
    const float* g = gt + (b * NG + gi) * 4;
    const float* p = pr + (b * NP + pi) * 4;
    float gx = g[0], gy = g[1], gw = g[2], gh = g[3];
    float px = p[0], py = p[1], pw = p[2], ph = p[3];
    float tlx = fmaxf(gx - gw * 0.5f, px - pw * 0.5f);
    float tly = fmaxf(gy - gh * 0.5f, py - ph * 0.5f);
    float brx = fminf(gx + gw * 0.5f, px + pw * 0.5f);
    float bry = fminf(gy + gh * 0.5f, py + ph * 0.5f);
    float en = ((tlx < brx) && (tly < bry)) ? 1.f : 0.f;
    float ai = (brx - tlx) * (bry - tly) * en;
    float iou = ai / (gw * gh + pw * ph - ai + 1e-16f);
    return (iou > 0.3f && pw > 2.f && ph > 2.f);
}

// ---- fused: crop + mu/sigma (blocks 0..959) | validity compaction (block 960) ----
__global__ __launch_bounds__(512) void k_crop_valid(const float* __restrict__ imgs,
                                                    const float* __restrict__ gt,
                                                    const float* __restrict__ pr,
                                                    float* __restrict__ crops,
                                                    float* __restrict__ mus,
                                                    float* __restrict__ sigs,
                                                    int* __restrict__ list,
                                                    int* __restrict__ count) {
    const int blk = blockIdx.x;
    const int t = threadIdx.x;
    const int wave = t >> 6, lane = t & 63;

    if (blk == 3 * NCROP) {
        // ---- validity -> compact list: 2-pass wave-local ballot, 1 barrier ----
        // 8 waves x 8 iterations x 64 lanes = 4096 pairs
        __shared__ int s_wcnt[8];
        int cnt = 0;
#pragma unroll 1
        for (int i = 0; i < 8; ++i) {
            unsigned long long m = __ballot(pair_valid(gt, pr, wave * 512 + i * 64 + lane));
            cnt += __popcll(m);
        }
        if (lane == 0) s_wcnt[wave] = cnt;
        __syncthreads();
        int base = 0;
#pragma unroll
        for (int w = 0; w < 8; ++w)
            if (w < wave) base += s_wcnt[w];
#pragma unroll 1
        for (int i = 0; i < 8; ++i) {
            int idx = wave * 512 + i * 64 + lane;
            bool v = pair_valid(gt, pr, idx);
            unsigned long long m = __ballot(v);
            if (v) list[base + __popcll(m & ((1ull << lane) - 1ull))] = idx;
            base += __popcll(m);
        }
        if (t == 0) {
            int s = 0;
#pragma unroll
            for (int w = 0; w < 8; ++w) s += s_wcnt[w];
            *count = s;
        }
        return;
    }

    // ---- crop path: 512 threads, 2 px/thread, per-thread bilinear float2 gathers ----
    const int crop = blk / 3;
    const int c = blk - crop * 3;
    int b;
    const float* box;
    if (crop < BB * NG) {
        b = crop >> 4;
        box = gt + crop * 4;
    } else {
        int id = crop - BB * NG;
        b = id >> 6;
        box = pr + id * 4;
    }

    // cr: column apron (x index shifted +5, cols 0..41 valid, 0..4 & 37..41 zero)
    // t1/t2: row apron (y index shifted +5, rows 0..41, 0..4 & 37..41 zero)
    __shared__ float cr[SZ][PSTA];
    __shared__ float t1[APR][PST];
    __shared__ float t2[APR][PST];

    // zero conv aprons once (taps into apron multiply exact 0.0f)
    for (int i = t; i < SZ * 10; i += 512) {
        int r = i / 10, cc = i % 10;
        cr[r][cc < 5 ? cc : cc + 32] = 0.f;
    }
    for (int i = t; i < 10 * PST; i += 512) {
        int r = i / PST, cc = i % PST;
        int rr = (r < 5) ? r : r + 32;
        t1[rr][cc] = 0.f;
        t2[rr][cc] = 0.f;
    }

    // box is wave-uniform -> scalar loads
    float cx = box[0], cy = box[1], bw = box[2], bh = box[3];
    float x0 = fminf(fmaxf(floorf(cx - bw * 0.5f), 0.f), (float)(IW - 1));
    float x1 = fminf(fmaxf(floorf(cx + bw * 0.5f), 0.f), (float)IW);
    float y0 = fminf(fmaxf(floorf(cy - bh * 0.5f), 0.f), (float)(IH - 1));
    float y1 = fminf(fmaxf(floorf(cy + bh * 0.5f), 0.f), (float)IH);
    float wp = fmaxf(x1 - x0, 1.f);
    float hp = fmaxf(y1 - y0, 1.f);
    int xmax = (int)(x0 + wp - 1.f);
    int ymax = (int)(y0 + hp - 1.f);

    const int y = t >> 4;          // thread owns pixels (y, xb..xb+1)
    const int xb = (t & 15) * 2;

    float sy = y0 + fminf(fmaxf(((float)y + 0.5f) * hp * (1.f / 32.f) - 0.5f, 0.f), hp - 1.f);
    float fly = floorf(sy);
    int iy0 = (int)fly;
    float fy = sy - fly;
    int iy1 = min(iy0 + 1, ymax);

    const float* ic = imgs + ((size_t)b * 3 + c) * IH * IW;
    const float* r0 = ic + iy0 * IW;
    const float* r1 = ic + iy1 * IW;
    float vv[2];
#pragma unroll
    for (int j = 0; j < 2; ++j) {
        int x = xb + j;
        float sx = x0 + fminf(fmaxf(((float)x + 0.5f) * wp * (1.f / 32.f) - 0.5f, 0.f), wp - 1.f);
        float flx = floorf(sx);
        int ix0 = (int)flx;
        float fx = sx - flx;
        // float2 gather: ix1==ix0+1 except at the clamp edge; clamped/degenerate
        // lanes have fx==0 or select f.y, so result is bitwise identical to the
        // 4-scalar-load version (0-weight taps multiply a finite value).
        int ixb = max(min(ix0, xmax - 1), 0);
        bool cl = (ix0 > ixb);     // ix0 was at xmax: duplicate high element
        float2 q0 = *(const float2*)(r0 + ixb);
        float2 q1 = *(const float2*)(r1 + ixb);
        float v00 = cl ? q0.y : q0.x;
        float v01 = q0.y;
        float v10 = cl ? q1.y : q1.x;
        float v11 = q1.y;
        vv[j] = v00 * (1.f - fy) * (1.f - fx) + v01 * (1.f - fy) * fx +
                v10 * fy * (1.f - fx) + v11 * fy * fx;
        cr[y][x + 5] = vv[j];
    }
    float* dst = crops + (size_t)crop * NPIX + c * CPIX + t * 2;
    *(float2*)dst = make_float2(vv[0], vv[1]);
    __syncthreads();

    constexpr float GW[WIN] = GW_INIT;
    // horizontal pass on x and x^2 — unconditional taps (apron = 0)
#pragma unroll
    for (int j = 0; j < 2; ++j) {
        int x = xb + j;
        float a1 = 0.f, a2 = 0.f;
#pragma unroll
        for (int k = 0; k < WIN; ++k) {
            float v = cr[y][x + k];        // conceptual col x+k-5, stored +5
            a1 += GW[k] * v;
            a2 += GW[k] * v * v;
        }
        t1[y + 5][x] = a1;
        t2[y + 5][x] = a2;
    }
    __syncthreads();
    // vertical pass — unconditional taps (apron = 0)
    float m[2], s[2];
#pragma unroll
    for (int j = 0; j < 2; ++j) {
        int x = xb + j;
        float a1 = 0.f, a2 = 0.f;
#pragma unroll
        for (int k = 0; k < WIN; ++k) {
            a1 += GW[k] * t1[y + k][x];    // conceptual row y+k-5, stored +5
            a2 += GW[k] * t2[y + k][x];
        }
        m[j] = a1;
        s[j] = a2 - a1 * a1;
    }
    float* mdst = mus + (size_t)crop * NPIX + c * CPIX + t * 2;
    float* sdst = sigs + (size_t)crop * NPIX + c * CPIX + t * 2;
    *(float2*)mdst = make_float2(m[0], m[1]);
    *(float2*)sdst = make_float2(s[0], s[1]);
}

// ---- per-(valid-pair, channel) SSIM + L1; unique-cell stores (r3/r7-measured-fast) ----
__global__ __launch_bounds__(256) void k_pair(const int* __restrict__ list,
                                              const int* __restrict__ count,
                                              const float* __restrict__ crops,
                                              const float* __restrict__ mus,
                                              const float* __restrict__ sigs,
                                              float* __restrict__ pairL1,
                                              float* __restrict__ pairSS) {
    const int c = blockIdx.x;      // 0..2
    const int n = *count;
    const int t = threadIdx.x;
    const int y = t >> 3;
    const int xb = (t & 7) * 4;
    const int wave = t >> 6, lane = t & 63;

    __shared__ float gp[SZ][PSTA];
    __shared__ float tmp[APR][PST];
    __shared__ float rl[4], rs[4];
    constexpr float GW[WIN] = GW_INIT;

    // zero conv aprons once; interior is rewritten each slot iteration
    for (int i = t; i < SZ * 10; i += 256) {
        int r = i / 10, cc = i % 10;
        gp[r][cc < 5 ? cc : cc + 32] = 0.f;
    }
    for (int i = t; i < 10 * PST; i += 256) {
        int r = i / PST, cc = i % PST;
        int rr = (r < 5) ? r : r + 32;
        tmp[rr][cc] = 0.f;
    }

    for (int slot = blockIdx.y; slot < n; slot += NSLOT) {
        const int pair = list[slot];
        const int b = pair >> 10;
        const int r = pair & 1023;
        const int gi = r >> 6, pi = r & 63;
        const size_t goff = (size_t)(b * NG + gi) * NPIX + c * CPIX;
        const size_t poff = (size_t)(BB * NG + b * NP + pi) * NPIX + c * CPIX;

        float4 gv = *(const float4*)(crops + goff + t * 4);
        float4 pv = *(const float4*)(crops + poff + t * 4);
        // hoist mu/sigma loads: in flight across both conv phases
        float4 mg = *(const float4*)(mus + goff + t * 4);
        float4 mp = *(const float4*)(mus + poff + t * 4);
        float4 sg = *(const float4*)(sigs + goff + t * 4);
        float4 sp = *(const float4*)(sigs + poff + t * 4);

        float l1 = fabsf(gv.x - pv.x) + fabsf(gv.y - pv.y) +
                   fabsf(gv.z - pv.z) + fabsf(gv.w - pv.w);
        gp[y][xb + 5] = gv.x * pv.x;
        gp[y][xb + 6] = gv.y * pv.y;
        gp[y][xb + 7] = gv.z * pv.z;
        gp[y][xb + 8] = gv.w * pv.w;
        __syncthreads();

#pragma unroll
        for (int j = 0; j < 4; ++j) {
            int x = xb + j;
            float a = 0.f;
#pragma unroll
            for (int k = 0; k < WIN; ++k) a += GW[k] * gp[y][x + k];
            tmp[y + 5][x] = a;
        }
        __syncthreads();

        float mgv[4] = {mg.x, mg.y, mg.z, mg.w};
        float mpv[4] = {mp.x, mp.y, mp.z, mp.w};
        float sgv[4] = {sg.x, sg.y, sg.z, sg.w};
        float spv[4] = {sp.x, sp.y, sp.z, sp.w};
        float ss = 0.f;
#pragma unroll
        for (int j = 0; j < 4; ++j) {
            int x = xb + j;
            float a = 0.f;
#pragma unroll
            for (int k = 0; k < WIN; ++k) a += GW[k] * tmp[y + k][x];
            float m1 = mgv[j], m2 = mpv[j];
            float sgp = a - m1 * m2;
            float num = (2.f * m1 * m2 + SSIM_C1) * (2.f * sgp + SSIM_C2);
            float den = (m1 * m1 + m2 * m2 + SSIM_C1) * (sgv[j] + spv[j] + SSIM_C2);
            ss += num / den;
        }

        // block reduction: 64-lane shuffle, then LDS across 4 waves
#pragma unroll
        for (int off = 32; off > 0; off >>= 1) {
            l1 += __shfl_down(l1, off);
            ss += __shfl_down(ss, off);
        }
        if (lane == 0) { rl[wave] = l1; rs[wave] = ss; }
        __syncthreads();
        if (t == 0) {
            pairL1[slot * 3 + c] = rl[0] + rl[1] + rl[2] + rl[3];
            pairSS[slot * 3 + c] = rs[0] + rs[1] + rs[2] + rs[3];
        }
    }
}

// ---- finalize: deterministic reduction over compact results ----
__global__ __launch_bounds__(256) void k_final(const int* __restrict__ count,
                                               const float* __restrict__ pairL1,
                                               const float* __restrict__ pairSS,
                                               float* __restrict__ out) {
    const int n3 = (*count) * 3;
    const int t = threadIdx.x;
    float L = 0.f, S = 0.f;
    for (int i = t; i < n3; i += 256) {
        L += pairL1[i];
        S += pairSS[i];
    }
    __shared__ float rl[4], rs[4];
#pragma unroll
    for (int off = 32; off > 0; off >>= 1) {
        L += __shfl_down(L, off);
        S += __shfl_down(S, off);
    }
    const int wave = t >> 6, lane = t & 63;
    if (lane == 0) { rl[wave] = L; rs[wave] = S; }
    __syncthreads();
    if (t == 0) {
        float cnt = (float)(*count);
        float Lt = (rl[0] + rl[1] + rl[2] + rl[3]) * (1.0f / (255.0f * (float)NPIX));
        float St = (rs[0] + rs[1] + rs[2] + rs[3]) * (1.0f / (float)NPIX);
        float m = fmaxf(cnt, 1.f);
        float loss = Lt / m + 1.f - St / m;
        out[0] = (cnt > 0.f) ? loss : 0.f;
    }
}

extern "C" void kernel_launch(void* const* d_in, const int* in_sizes, int n_in,
                              void* d_out, int out_size, void* d_ws, size_t ws_size,
                              hipStream_t stream) {
    const float* imgs = (const float*)d_in[0];  // (4,3,640,640)
    const float* gt = (const float*)d_in[1];    // (4,16,4)
    const float* pr = (const float*)d_in[2];    // (4,64,4)

    float* ws = (float*)d_ws;
    float* crops = ws;                                   // 320*3072
    float* mus = crops + (size_t)NCROP * NPIX;
    float* sigs = mus + (size_t)NCROP * NPIX;
    float* pairL1 = sigs + (size_t)NCROP * NPIX;         // 4096*3
    float* pairSS = pairL1 + (size_t)NPAIR * 3;          // 4096*3
    int* list = (int*)(pairSS + (size_t)NPAIR * 3);      // 4096
    int* count = list + NPAIR;                           // 1

    k_crop_valid<<<3 * NCROP + 1, 512, 0, stream>>>(imgs, gt, pr, crops, mus, sigs,
                                                    list, count);
    k_pair<<<dim3(3, NSLOT), 256, 0, stream>>>(list, count, crops, mus, sigs,
                                               pairL1, pairSS);
    k_final<<<1, 256, 0, stream>>>(count, pairL1, pairSS, (float*)d_out);
}

// Round 5
// 81.434 us; speedup vs baseline: 1.1957x; 1.0037x over previous
//
#include <hip/hip_runtime.h>
#include <math.h>

#define WIN 11
#define HALF 5
#define SZ 32
#define PST 33          /* padded LDS row stride (row-apron arrays) */
#define PSTA 45         /* stride for column-apron arrays: 42 cols used, odd stride -> <=2-way bank alias (free, m136) */
#define APR 42          /* 32 + 2*5 apron */
#define BB 4
#define NG 16
#define NP 64
#define IH 640
#define IW 640
#define CPIX 1024       /* 32*32 per channel */
#define NPIX 3072       /* 3*32*32 per crop */
#define NCROP 320       /* 64 gt + 256 pred */
#define NPAIR 4096      /* 4*16*64 */
#define NSLOT 512       /* k_pair y-blocks per channel */
#define SSIM_C1 6.5025f
#define SSIM_C2 58.5225f

// exp(-(i-5)^2/4.5)/sum — 11-tap Gaussian, sigma=1.5, compile-time
#define GW_INIT {0.001028379f, 0.007598757f, 0.036000791f, 0.109360748f, \
                 0.213005174f, 0.266011868f, 0.213005174f, 0.109360748f, \
                 0.036000791f, 0.007598757f, 0.001028379f}

// Session lessons encoded:
//  - NO __threadfence (r5: device-scope fence flushes per-XCD L2; +100 µs over 1.5k blocks).
//  - NO contended fp atomicAdd accumulation (r2/r6 vs r3/r7: +16 µs); unique-cell
//    stores + tiny reduce kernel.
//  - NO memset dispatch: ballot compaction writes count/list with plain stores.
//  - r8: do NOT re-gather crops per pair (scattered gathers are the expensive op).
//  - r9: do NOT move per-crop stats (mu/sigma convs) into the per-pair kernel
//    (2.8x conv work + 30KB LDS = +6 µs). Compute each quantity at the loop
//    level where it naturally lives. r7 split is optimal so far.
//  - r10: bilinear gather via float2 (16->8 load instrs; clamp edges have
//    weight exactly 0 so result is bitwise identical).
//  - r11 FAILED (+8.6 µs): folding k_final into k_pair via a per-block
//    AGENT-scope ACQ_REL ticket. Device-scope ordered atomics writeback/
//    invalidate the issuing XCD's L2 (coherence point is L3) -> ~900 flushes.
//    Same family as r5. A 1-block k_final dispatch is CHEAPER than any
//    cross-block completion protocol. Keep 3 kernels.
//  - r12/r13 WIN (-3.2 µs): zero-padded LDS aprons -> unconditional conv taps
//    (apron taps multiply exact 0.0f, bitwise identical). 85.6 µs.
//  - r14 WIN (-3.9 µs): k_crop_valid at 512 threads (2 px/thread); doubled
//    resident waves for gather-latency hiding. 81.7 µs.
//  - r15 (this round): XCD-locality block remap in k_crop_valid. pred crops
//    are tiled copies of gt crops (+noise): each gt's source region is read
//    5x. Default round-robin scatters the 15 related blocks (5 crops x 3 ch)
//    across all 8 non-coherent L2s -> 5x cold-HBM fetches. Remap so each
//    gt-group's 15 blocks land on one XCD (xcd ~= blk%8 heuristic): 4/5 of
//    gathers become same-XCD L2 hits. Index permutation only.

__device__ __forceinline__ bool pair_valid(const float* __restrict__ gt,
                                           const float* __restrict__ pr, int idx) {
    int b = idx >> 10;
    int r = idx & 1023;
    int gi = r >> 6, pi = r & 63;
    const float* g = gt + (b * NG + gi) * 4;
    const float* p = pr + (b * NP + pi) * 4;
    float gx = g[0], gy = g[1], gw = g[2], gh = g[3];
    float px = p[0], py = p[1], pw = p[2], ph = p[3];
    float tlx = fmaxf(gx - gw * 0.5f, px - pw * 0.5f);
    float tly = fmaxf(gy - gh * 0.5f, py - ph * 0.5f);
    float brx = fminf(gx + gw * 0.5f, px + pw * 0.5f);
    float bry = fminf(gy + gh * 0.5f, py + ph * 0.5f);
    float en = ((tlx < brx) && (tly < bry)) ? 1.f : 0.f;
    float ai = (brx - tlx) * (bry - tly) * en;
    float iou = ai / (gw * gh + pw * ph - ai + 1e-16f);
    return (iou > 0.3f && pw > 2.f && ph > 2.f);
}

// ---- fused: crop + mu/sigma (blocks 0..959) | validity compaction (block 960) ----
__global__ __launch_bounds__(512) void k_crop_valid(const float* __restrict__ imgs,
                                                    const float* __restrict__ gt,
                                                    const float* __restrict__ pr,
                                                    float* __restrict__ crops,
                                                    float* __restrict__ mus,
                                                    float* __restrict__ sigs,
                                                    int* __restrict__ list,
                                                    int* __restrict__ count) {
    const int blk = blockIdx.x;
    const int t = threadIdx.x;
    const int wave = t >> 6, lane = t & 63;

    if (blk == 3 * NCROP) {
        // ---- validity -> compact list: 2-pass wave-local ballot, 1 barrier ----
        // 8 waves x 8 iterations x 64 lanes = 4096 pairs
        __shared__ int s_wcnt[8];
        int cnt = 0;
#pragma unroll 1
        for (int i = 0; i < 8; ++i) {
            unsigned long long m = __ballot(pair_valid(gt, pr, wave * 512 + i * 64 + lane));
            cnt += __popcll(m);
        }
        if (lane == 0) s_wcnt[wave] = cnt;
        __syncthreads();
        int base = 0;
#pragma unroll
        for (int w = 0; w < 8; ++w)
            if (w < wave) base += s_wcnt[w];
#pragma unroll 1
        for (int i = 0; i < 8; ++i) {
            int idx = wave * 512 + i * 64 + lane;
            bool v = pair_valid(gt, pr, idx);
            unsigned long long m = __ballot(v);
            if (v) list[base + __popcll(m & ((1ull << lane) - 1ull))] = idx;
            base += __popcll(m);
        }
        if (t == 0) {
            int s = 0;
#pragma unroll
            for (int w = 0; w < 8; ++w) s += s_wcnt[w];
            *count = s;
        }
        return;
    }

    // ---- XCD-locality remap: physical blk -> (xcd, q). The 15 blocks of one
    // gt-group (gt crop i + its 4 tiled pred crops, x3 channels) share one XCD
    // (dispatch heuristic xcd ~= blk%8), so their overlapping source regions
    // hit that XCD's L2 instead of 5x cold-HBM. 960 = 8 xcd * 8 ghi * 15 m. ----
    const int xcd = blk & 7;
    const int q = blk >> 3;
    const int ghi = q / 15;          // 0..7
    const int m15 = q - ghi * 15;    // 0..14
    const int g = ghi * 8 + xcd;     // gt-group 0..63
    const int gb = g >> 4, gi = g & 15;   // batch, gt-index
    const int cg = m15 / 3;          // 0 = gt crop, 1..4 = tiled pred crops
    const int c = m15 - cg * 3;      // channel
    int crop;
    if (cg == 0) crop = gb * NG + gi;
    else crop = BB * NG + gb * NP + gi + (cg - 1) * 16;
    const int b = gb;
    const float* box = (cg == 0) ? gt + crop * 4 : pr + (crop - BB * NG) * 4;

    // cr: column apron (x index shifted +5, cols 0..41 valid, 0..4 & 37..41 zero)
    // t1/t2: row apron (y index shifted +5, rows 0..41, 0..4 & 37..41 zero)
    __shared__ float cr[SZ][PSTA];
    __shared__ float t1[APR][PST];
    __shared__ float t2[APR][PST];

    // zero conv aprons once (taps into apron multiply exact 0.0f)
    for (int i = t; i < SZ * 10; i += 512) {
        int r = i / 10, cc = i % 10;
        cr[r][cc < 5 ? cc : cc + 32] = 0.f;
    }
    for (int i = t; i < 10 * PST; i += 512) {
        int r = i / PST, cc = i % PST;
        int rr = (r < 5) ? r : r + 32;
        t1[rr][cc] = 0.f;
        t2[rr][cc] = 0.f;
    }

    // box is wave-uniform -> scalar loads
    float cx = box[0], cy = box[1], bw = box[2], bh = box[3];
    float x0 = fminf(fmaxf(floorf(cx - bw * 0.5f), 0.f), (float)(IW - 1));
    float x1 = fminf(fmaxf(floorf(cx + bw * 0.5f), 0.f), (float)IW);
    float y0 = fminf(fmaxf(floorf(cy - bh * 0.5f), 0.f), (float)(IH - 1));
    float y1 = fminf(fmaxf(floorf(cy + bh * 0.5f), 0.f), (float)IH);
    float wp = fmaxf(x1 - x0, 1.f);
    float hp = fmaxf(y1 - y0, 1.f);
    int xmax = (int)(x0 + wp - 1.f);
    int ymax = (int)(y0 + hp - 1.f);

    const int y = t >> 4;          // thread owns pixels (y, xb..xb+1)
    const int xb = (t & 15) * 2;

    float sy = y0 + fminf(fmaxf(((float)y + 0.5f) * hp * (1.f / 32.f) - 0.5f, 0.f), hp - 1.f);
    float fly = floorf(sy);
    int iy0 = (int)fly;
    float fy = sy - fly;
    int iy1 = min(iy0 + 1, ymax);

    const float* ic = imgs + ((size_t)b * 3 + c) * IH * IW;
    const float* r0 = ic + iy0 * IW;
    const float* r1 = ic + iy1 * IW;
    float vv[2];
#pragma unroll
    for (int j = 0; j < 2; ++j) {
        int x = xb + j;
        float sx = x0 + fminf(fmaxf(((float)x + 0.5f) * wp * (1.f / 32.f) - 0.5f, 0.f), wp - 1.f);
        float flx = floorf(sx);
        int ix0 = (int)flx;
        float fx = sx - flx;
        // float2 gather: ix1==ix0+1 except at the clamp edge; clamped/degenerate
        // lanes have fx==0 or select f.y, so result is bitwise identical to the
        // 4-scalar-load version (0-weight taps multiply a finite value).
        int ixb = max(min(ix0, xmax - 1), 0);
        bool cl = (ix0 > ixb);     // ix0 was at xmax: duplicate high element
        float2 q0 = *(const float2*)(r0 + ixb);
        float2 q1 = *(const float2*)(r1 + ixb);
        float v00 = cl ? q0.y : q0.x;
        float v01 = q0.y;
        float v10 = cl ? q1.y : q1.x;
        float v11 = q1.y;
        vv[j] = v00 * (1.f - fy) * (1.f - fx) + v01 * (1.f - fy) * fx +
                v10 * fy * (1.f - fx) + v11 * fy * fx;
        cr[y][x + 5] = vv[j];
    }
    float* dst = crops + (size_t)crop * NPIX + c * CPIX + t * 2;
    *(float2*)dst = make_float2(vv[0], vv[1]);
    __syncthreads();

    constexpr float GW[WIN] = GW_INIT;
    // horizontal pass on x and x^2 — unconditional taps (apron = 0)
#pragma unroll
    for (int j = 0; j < 2; ++j) {
        int x = xb + j;
        float a1 = 0.f, a2 = 0.f;
#pragma unroll
        for (int k = 0; k < WIN; ++k) {
            float v = cr[y][x + k];        // conceptual col x+k-5, stored +5
            a1 += GW[k] * v;
            a2 += GW[k] * v * v;
        }
        t1[y + 5][x] = a1;
        t2[y + 5][x] = a2;
    }
    __syncthreads();
    // vertical pass — unconditional taps (apron = 0)
    float m[2], s[2];
#pragma unroll
    for (int j = 0; j < 2; ++j) {
        int x = xb + j;
        float a1 = 0.f, a2 = 0.f;
#pragma unroll
        for (int k = 0; k < WIN; ++k) {
            a1 += GW[k] * t1[y + k][x];    // conceptual row y+k-5, stored +5
            a2 += GW[k] * t2[y + k][x];
        }
        m[j] = a1;
        s[j] = a2 - a1 * a1;
    }
    float* mdst = mus + (size_t)crop * NPIX + c * CPIX + t * 2;
    float* sdst = sigs + (size_t)crop * NPIX + c * CPIX + t * 2;
    *(float2*)mdst = make_float2(m[0], m[1]);
    *(float2*)sdst = make_float2(s[0], s[1]);
}

// ---- per-(valid-pair, channel) SSIM + L1; unique-cell stores (r3/r7-measured-fast) ----
__global__ __launch_bounds__(256) void k_pair(const int* __restrict__ list,
                                              const int* __restrict__ count,
                                              const float* __restrict__ crops,
                                              const float* __restrict__ mus,
                                              const float* __restrict__ sigs,
                                              float* __restrict__ pairL1,
                                              float* __restrict__ pairSS) {
    const int c = blockIdx.x;      // 0..2
    const int n = *count;
    const int t = threadIdx.x;
    const int y = t >> 3;
    const int xb = (t & 7) * 4;
    const int wave = t >> 6, lane = t & 63;

    __shared__ float gp[SZ][PSTA];
    __shared__ float tmp[APR][PST];
    __shared__ float rl[4], rs[4];
    constexpr float GW[WIN] = GW_INIT;

    // zero conv aprons once; interior is rewritten each slot iteration
    for (int i = t; i < SZ * 10; i += 256) {
        int r = i / 10, cc = i % 10;
        gp[r][cc < 5 ? cc : cc + 32] = 0.f;
    }
    for (int i = t; i < 10 * PST; i += 256) {
        int r = i / PST, cc = i % PST;
        int rr = (r < 5) ? r : r + 32;
        tmp[rr][cc] = 0.f;
    }

    for (int slot = blockIdx.y; slot < n; slot += NSLOT) {
        const int pair = list[slot];
        const int b = pair >> 10;
        const int r = pair & 1023;
        const int gi = r >> 6, pi = r & 63;
        const size_t goff = (size_t)(b * NG + gi) * NPIX + c * CPIX;
        const size_t poff = (size_t)(BB * NG + b * NP + pi) * NPIX + c * CPIX;

        float4 gv = *(const float4*)(crops + goff + t * 4);
        float4 pv = *(const float4*)(crops + poff + t * 4);
        // hoist mu/sigma loads: in flight across both conv phases
        float4 mg = *(const float4*)(mus + goff + t * 4);
        float4 mp = *(const float4*)(mus + poff + t * 4);
        float4 sg = *(const float4*)(sigs + goff + t * 4);
        float4 sp = *(const float4*)(sigs + poff + t * 4);

        float l1 = fabsf(gv.x - pv.x) + fabsf(gv.y - pv.y) +
                   fabsf(gv.z - pv.z) + fabsf(gv.w - pv.w);
        gp[y][xb + 5] = gv.x * pv.x;
        gp[y][xb + 6] = gv.y * pv.y;
        gp[y][xb + 7] = gv.z * pv.z;
        gp[y][xb + 8] = gv.w * pv.w;
        __syncthreads();

#pragma unroll
        for (int j = 0; j < 4; ++j) {
            int x = xb + j;
            float a = 0.f;
#pragma unroll
            for (int k = 0; k < WIN; ++k) a += GW[k] * gp[y][x + k];
            tmp[y + 5][x] = a;
        }
        __syncthreads();

        float mgv[4] = {mg.x, mg.y, mg.z, mg.w};
        float mpv[4] = {mp.x, mp.y, mp.z, mp.w};
        float sgv[4] = {sg.x, sg.y, sg.z, sg.w};
        float spv[4] = {sp.x, sp.y, sp.z, sp.w};
        float ss = 0.f;
#pragma unroll
        for (int j = 0; j < 4; ++j) {
            int x = xb + j;
            float a = 0.f;
#pragma unroll
            for (int k = 0; k < WIN; ++k) a += GW[k] * tmp[y + k][x];
            float m1 = mgv[j], m2 = mpv[j];
            float sgp = a - m1 * m2;
            float num = (2.f * m1 * m2 + SSIM_C1) * (2.f * sgp + SSIM_C2);
            float den = (m1 * m1 + m2 * m2 + SSIM_C1) * (sgv[j] + spv[j] + SSIM_C2);
            ss += num / den;
        }

        // block reduction: 64-lane shuffle, then LDS across 4 waves
#pragma unroll
        for (int off = 32; off > 0; off >>= 1) {
            l1 += __shfl_down(l1, off);
            ss += __shfl_down(ss, off);
        }
        if (lane == 0) { rl[wave] = l1; rs[wave] = ss; }
        __syncthreads();
        if (t == 0) {
            pairL1[slot * 3 + c] = rl[0] + rl[1] + rl[2] + rl[3];
            pairSS[slot * 3 + c] = rs[0] + rs[1] + rs[2] + rs[3];
        }
    }
}

// ---- finalize: deterministic reduction over compact results ----
__global__ __launch_bounds__(256) void k_final(const int* __restrict__ count,
                                               const float* __restrict__ pairL1,
                                               const float* __restrict__ pairSS,
                                               float* __restrict__ out) {
    const int n3 = (*count) * 3;
    const int t = threadIdx.x;
    float L = 0.f, S = 0.f;
    for (int i = t; i < n3; i += 256) {
        L += pairL1[i];
        S += pairSS[i];
    }
    __shared__ float rl[4], rs[4];
#pragma unroll
    for (int off = 32; off > 0; off >>= 1) {
        L += __shfl_down(L, off);
        S += __shfl_down(S, off);
    }
    const int wave = t >> 6, lane = t & 63;
    if (lane == 0) { rl[wave] = L; rs[wave] = S; }
    __syncthreads();
    if (t == 0) {
        float cnt = (float)(*count);
        float Lt = (rl[0] + rl[1] + rl[2] + rl[3]) * (1.0f / (255.0f * (float)NPIX));
        float St = (rs[0] + rs[1] + rs[2] + rs[3]) * (1.0f / (float)NPIX);
        float m = fmaxf(cnt, 1.f);
        float loss = Lt / m + 1.f - St / m;
        out[0] = (cnt > 0.f) ? loss : 0.f;
    }
}

extern "C" void kernel_launch(void* const* d_in, const int* in_sizes, int n_in,
                              void* d_out, int out_size, void* d_ws, size_t ws_size,
                              hipStream_t stream) {
    const float* imgs = (const float*)d_in[0];  // (4,3,640,640)
    const float* gt = (const float*)d_in[1];    // (4,16,4)
    const float* pr = (const float*)d_in[2];    // (4,64,4)

    float* ws = (float*)d_ws;
    float* crops = ws;                                   // 320*3072
    float* mus = crops + (size_t)NCROP * NPIX;
    float* sigs = mus + (size_t)NCROP * NPIX;
    float* pairL1 = sigs + (size_t)NCROP * NPIX;         // 4096*3
    float* pairSS = pairL1 + (size_t)NPAIR * 3;          // 4096*3
    int* list = (int*)(pairSS + (size_t)NPAIR * 3);      // 4096
    int* count = list + NPAIR;                           // 1

    k_crop_valid<<<3 * NCROP + 1, 512, 0, stream>>>(imgs, gt, pr, crops, mus, sigs,
                                                    list, count);
    k_pair<<<dim3(3, NSLOT), 256, 0, stream>>>(list, count, crops, mus, sigs,
                                               pairL1, pairSS);
    k_final<<<1, 256, 0, stream>>>(count, pairL1, pairSS, (float*)d_out);
}